// Round 1
// 64.458 us; speedup vs baseline: 1.0217x; 1.0217x over previous
//
#include <hip/hip_runtime.h>
#include <math.h>

constexpr int Lc = 8192;   // sequence length
constexpr int Kc = 32;     // eigenvectors
constexpr int Bc = 64;     // batch
constexpr int NSLICE = 32; // conv tap-slices (128 odd taps each)
constexpr int NCHUNK = 8;  // conv n-chunks (1024 outputs each)

// cot(pi*d/L) in fp32, reflected for d > L/2 to avoid cancellation near pi.
__device__ inline float cot_pi_frac_f(int d) {
    int dd = d; float s = 1.0f;
    if (dd > Lc / 2) { dd = Lc - dd; s = -1.0f; }
    float ang = (float)(M_PI * (double)dd / (double)Lc);
    return s * __fdividef(__cosf(ang), __sinf(ang));
}

// Math (validated R1-R3 of previous session):
//   out[b][n] = sr[b]*w[n] + si2[b]*Bsum[n]
//   w[n]   = sum_k lam[k] ev[k][n]
//   sr[b]  = sum_{even n} u[b][n] + 4096*u[b][0]      (DC weight 4097)
//   si2[b] = (2/L) * sum_m u[b][2m+1] * c[m],  c[m] = cot(pi(2m+1)/L)
//   Bsum[n]= sum_m c[m] * w[(n-2m-1) mod L]           (signs absorbed)

// K0: precompute w once (was rebuilt per conv block = 40x redundancy).
__global__ __launch_bounds__(256) void k_w(
    const float* __restrict__ ev, const float* __restrict__ lam,
    float* __restrict__ wbuf)
{
    const int n = blockIdx.x * 256 + threadIdx.x;
    float wv = 0.f;
#pragma unroll
    for (int k = 0; k < Kc; ++k)
        wv = fmaf(lam[k], ev[(size_t)k * Lc + n], wv);
    wbuf[n] = wv;
}

// K1: blocks 0..63 = sigma (HBM-bound, overlaps), 64..319 = conv slices.
// Conv block: w-window LOADED from precomputed wbuf (320 float4 loads,
// was 10240 ev loads + 40960 FMA), parity-split into LDS.
__global__ __launch_bounds__(256) void k_main(
    const float* __restrict__ u, const float* __restrict__ wbuf,
    float* __restrict__ sr, float* __restrict__ si2, float* __restrict__ Bp)
{
    const int t = threadIdx.x;

    if (blockIdx.x < 64) {
        // ---------------- sigma: per-batch scalar reduction -----------------
        int b = blockIdx.x;
        const float4* u4 = (const float4*)(u + (size_t)b * Lc);
        float ar0 = 0.f, ar1 = 0.f, ai0 = 0.f, ai1 = 0.f;
#pragma unroll
        for (int i = 0; i < 8; ++i) {
            int j = t + 256 * i;
            float4 v = u4[j];
            ar0 += v.x; ar1 += v.z;
            ai0 = fmaf(v.y, cot_pi_frac_f(4 * j + 1), ai0);
            ai1 = fmaf(v.w, cot_pi_frac_f(4 * j + 3), ai1);
        }
        if (t == 0) ar0 += 4096.0f * u[(size_t)b * Lc];
        float ar = ar0 + ar1, ai = ai0 + ai1;
        for (int off = 32; off > 0; off >>= 1) {
            ar += __shfl_down(ar, off);
            ai += __shfl_down(ai, off);
        }
        __shared__ float red[8];
        int wave = t >> 6, lane = t & 63;
        if (lane == 0) { red[wave] = ar; red[4 + wave] = ai; }
        __syncthreads();
        if (t == 0) {
            sr[b]  = red[0] + red[1] + red[2] + red[3];
            si2[b] = (2.0f / (float)Lc) * (red[4] + red[5] + red[6] + red[7]);
        }
        return;
    }

    // ---------------- conv: register-tiled circular FIR ---------------------
    __shared__ float s_we[643];               // s_we[j] = w[A + 2j]
    __shared__ float s_wo[643];               // s_wo[j] = w[A + 2j + 1]
    __shared__ __align__(16) float s_c[128];  // reversed tap slice

    const int blk = blockIdx.x - 64;
    const int cn = blk & (NCHUNK - 1);
    const int sl = blk >> 3;
    const int n0 = cn * 1024;
    const int dbase = sl * 256;
    const int A = n0 - dbase - 256;           // 4-aligned window base

    // w-window: w[A .. A+1279] via float4 loads from precomputed wbuf.
#pragma unroll
    for (int it = 0; it < 2; ++it) {
        int gq = t + 256 * it;
        if (gq < 320) {
            int pos = (A + 4 * gq + 2 * Lc) & (Lc - 1);   // 4-aligned, no wrap inside quad
            float4 v = *(const float4*)(wbuf + pos);
            s_we[2 * gq]     = v.x; s_wo[2 * gq]     = v.y;
            s_we[2 * gq + 1] = v.z; s_wo[2 * gq + 1] = v.w;
        }
    }
    // Reversed tap slice: s_c[mm] = cot(pi*(dbase + 255 - 2mm)/L)
    if (t < 128) s_c[t] = cot_pi_frac_f(dbase + 255 - 2 * t);
    __syncthreads();

    // Thread t: g=t>>1, p=t&1; outputs n0+8g+p+2r, r=0..3, shared 7-reg window.
    const int g = t >> 1, p = t & 1;
    const float* s_wp = p ? (s_we + 1) : s_wo;   // parity remap (A=wbase-1)
    const int jb = 4 * g;

    float W0 = s_wp[jb],     W1 = s_wp[jb + 1], W2 = s_wp[jb + 2], W3 = s_wp[jb + 3];
    float W4 = s_wp[jb + 4], W5 = s_wp[jb + 5], W6 = s_wp[jb + 6];
    float a0 = 0.f, a1 = 0.f, a2 = 0.f, a3 = 0.f;

    const float4* s_c4 = (const float4*)s_c;
#pragma unroll
    for (int G = 0; G < 32; ++G) {
        const int mm0 = 4 * G;
        float4 cv = s_c4[G];                     // one ds_read_b128
        a0 = fmaf(cv.x, W0, a0); a1 = fmaf(cv.x, W1, a1); a2 = fmaf(cv.x, W2, a2); a3 = fmaf(cv.x, W3, a3);
        a0 = fmaf(cv.y, W1, a0); a1 = fmaf(cv.y, W2, a1); a2 = fmaf(cv.y, W3, a2); a3 = fmaf(cv.y, W4, a3);
        a0 = fmaf(cv.z, W2, a0); a1 = fmaf(cv.z, W3, a1); a2 = fmaf(cv.z, W4, a2); a3 = fmaf(cv.z, W5, a3);
        a0 = fmaf(cv.w, W3, a0); a1 = fmaf(cv.w, W4, a1); a2 = fmaf(cv.w, W5, a2); a3 = fmaf(cv.w, W6, a3);
        if (G < 31) {
            W0 = W4; W1 = W5; W2 = W6;
            W3 = s_wp[jb + mm0 + 7];  W4 = s_wp[jb + mm0 + 8];
            W5 = s_wp[jb + mm0 + 9];  W6 = s_wp[jb + mm0 + 10];
        }
    }
    float* dst = Bp + (size_t)sl * Lc + n0 + 8 * g + p;
    dst[0] = a0; dst[2] = a1; dst[4] = a2; dst[6] = a3;
}

// K2: reduce 32 partials + rank-2 epilogue; w loaded from wbuf (was 32 ev loads).
__global__ __launch_bounds__(256) void k_out(
    const float* __restrict__ wbuf,
    const float* __restrict__ sr, const float* __restrict__ si2,
    const float* __restrict__ Bp, float* __restrict__ out)
{
    __shared__ float s_sv[128];
    const int t = threadIdx.x;
    if (t < 128) s_sv[t] = (t < 64) ? sr[t] : si2[t - 64];
    const int cn = blockIdx.x & 31, bg = blockIdx.x >> 5;
    const int n = cn * 256 + t;
    float wv = wbuf[n];
    float bsum = 0.f;
#pragma unroll
    for (int s = 0; s < NSLICE; ++s) bsum += Bp[(size_t)s * Lc + n];
    __syncthreads();
#pragma unroll
    for (int j = 0; j < 8; ++j) {
        int b = bg * 8 + j;
        out[(size_t)b * Lc + n] = fmaf(s_sv[b], wv, s_sv[64 + b] * bsum);
    }
}

extern "C" void kernel_launch(void* const* d_in, const int* in_sizes, int n_in,
                              void* d_out, int out_size, void* d_ws, size_t ws_size,
                              hipStream_t stream) {
    const float* u   = (const float*)d_in[0];  // (64, 8192)
    const float* ev  = (const float*)d_in[1];  // (32, 8192)
    const float* lam = (const float*)d_in[2];  // (32,)
    float* out = (float*)d_out;                // (64, 8192)

    float* ws   = (float*)d_ws;
    float* sr   = ws;                   // 64
    float* si2  = ws + 64;              // 64
    float* wbuf = ws + 128;             // 8192 (16B-aligned: byte offset 512)
    float* Bp   = ws + 128 + Lc;        // 32 * 8192

    hipLaunchKernelGGL(k_w,    dim3(Lc / 256), dim3(256), 0, stream, ev, lam, wbuf);
    hipLaunchKernelGGL(k_main, dim3(64 + NCHUNK * NSLICE), dim3(256), 0, stream,
                       u, wbuf, sr, si2, Bp);
    hipLaunchKernelGGL(k_out,  dim3(256), dim3(256), 0, stream,
                       wbuf, sr, si2, Bp, out);
}